// Round 4
// baseline (24987.183 us; speedup 1.0000x reference)
//
#include <hip/hip_runtime.h>
#include <hip/hip_bf16.h>
#include <math.h>

#define TPB 1024
#define NB 32
#define NT 64
#define NH 512
#define NM 128
#define NR 4
#define NW 64
#define NI 768          // controller input size (H + R*W)
#define NXI 471         // interface vector size
#define EPSF 1e-6f
#define MS 65           // mem row stride (+1 pad)

__device__ __forceinline__ float sigm(float x){ return 1.0f/(1.0f+expf(-x)); }
__device__ __forceinline__ float sftp(float x){ return fmaxf(x,0.0f)+log1pf(expf(-fabsf(x))); }

__global__ __launch_bounds__(TPB) void dnc_kernel(
    const float* __restrict__ x, const float* __restrict__ W_ih,
    const float* __restrict__ W_hh, const float* __restrict__ b_ih,
    const float* __restrict__ b_hh, const float* __restrict__ W_xi,
    const float* __restrict__ b_xi, const float* __restrict__ W_o,
    const float* __restrict__ b_o, float* __restrict__ out,
    float* __restrict__ ws)
{
    // -------- dedicated LDS, no aliasing anywhere --------
    __shared__ float mem[NM*MS];          // 8320
    __shared__ float hS[NH], cS[NH];
    __shared__ float rwS[NR*NM];
    __shared__ float wwO[NM], wwN[NM];
    __shared__ float usg[NM], prc[NM];
    __shared__ float inp[NI];             // [x_t | last_read]
    __shared__ float gts[4*NH];
    __shared__ float xiS[NXI+1];
    __shared__ float keys[NR*NW];
    __shared__ float wkey[NW], ers[NW], wvec[NW];
    __shared__ float rstr[NR], fgte[NR], modes[NR*3], nkey[NR];
    __shared__ float sc[8];               // 0:wstr 1:ag 2:wg 3:|wkey| 4:sum(ww)
    __shared__ float nmo[NM], nmn[NM];
    __shared__ float wcw[NM], uu[NM], su[NM], cum[NM];
    __shared__ int   rnk[NM];
    __shared__ float ccw[NR*NM];
    __shared__ float rv[NR*NW];
    __shared__ float red[8];

    const int tid = threadIdx.x;
    const int b = blockIdx.x;
    float* __restrict__ link = ws + (size_t)b*(NM*NM);

    // -------- init carry (ws/out re-poisoned before every launch) --------
    for (int e = tid; e < NM*NM; e += TPB) link[e] = 0.0f;
    for (int e = tid; e < NM*NW; e += TPB) mem[(e>>6)*MS + (e&63)] = EPSF;
    for (int e = tid; e < NH; e += TPB){ hS[e]=0.0f; cS[e]=0.0f; }
    for (int e = tid; e < NR*NM; e += TPB) rwS[e]=0.0f;
    for (int e = tid; e < NM; e += TPB){ wwO[e]=0.0f; usg[e]=0.0f; prc[e]=0.0f; }
    for (int e = tid; e < NR*NW; e += TPB) inp[NH+e]=0.0f;
    __syncthreads();

    for (int t = 0; t < NT; ++t) {
        // ---- A: x_t -> inp[0:512] (inp[512:768] = last_read, carried) ----
        if (tid < NH) inp[tid] = x[((size_t)b*NT + t)*NH + tid];
        __syncthreads();

        // ---- B: gates[j] = b_ih+b_hh + W_ih[j,:].inp + W_hh[j,:].h_old ----
        for (int jj = 0; jj < 2; ++jj) {
            const int j = tid + jj*TPB;
            const float4* wa = (const float4*)(W_ih + (size_t)j*NI);
            const float4* wb = (const float4*)(W_hh + (size_t)j*NH);
            float acc = b_ih[j] + b_hh[j];
            #pragma unroll 4
            for (int k = 0; k < NI/4; ++k) {
                float4 w = wa[k];
                acc += w.x*inp[4*k] + w.y*inp[4*k+1] + w.z*inp[4*k+2] + w.w*inp[4*k+3];
            }
            #pragma unroll 4
            for (int k = 0; k < NH/4; ++k) {
                float4 w = wb[k];
                acc += w.x*hS[4*k] + w.y*hS[4*k+1] + w.z*hS[4*k+2] + w.w*hS[4*k+3];
            }
            gts[j] = acc;
        }
        __syncthreads();

        // ---- C: LSTM pointwise, gate order i|f|g|o ----
        if (tid < NH) {
            float ig = sigm(gts[tid]);
            float fg = sigm(gts[NH + tid]);
            float gg = tanhf(gts[2*NH + tid]);
            float og = sigm(gts[3*NH + tid]);
            float c = fg*cS[tid] + ig*gg;
            cS[tid] = c;
            hS[tid] = og*tanhf(c);
        }
        __syncthreads();

        // ---- D: xi[j] = b_xi + W_xi[j,:].h_new ----
        if (tid < NXI) {
            const float4* wc = (const float4*)(W_xi + (size_t)tid*NH);
            float acc = b_xi[tid];
            #pragma unroll 4
            for (int k = 0; k < NH/4; ++k) {
                float4 w = wc[k];
                acc += w.x*hS[4*k] + w.y*hS[4*k+1] + w.z*hS[4*k+2] + w.w*hS[4*k+3];
            }
            xiS[tid] = acc;
        }
        __syncthreads();

        // ---- E1: unpack interface (splits 256|260|324|325|389|453|457|458|459) ----
        if (tid < 256)       keys[tid] = tanhf(xiS[tid]);
        else if (tid < 260)  rstr[tid-256] = sftp(xiS[tid]);
        else if (tid < 324)  wkey[tid-260] = tanhf(xiS[tid]);
        else if (tid == 324) sc[0] = sftp(xiS[324]);
        else if (tid < 389)  ers[tid-325] = sigm(xiS[tid]);
        else if (tid < 453)  wvec[tid-389] = tanhf(xiS[tid]);
        else if (tid < 457)  fgte[tid-453] = sigm(xiS[tid]);
        else if (tid == 457) sc[1] = sigm(xiS[457]);
        else if (tid == 458) sc[2] = sigm(xiS[458]);
        else if (tid < 463) {                 // read-mode softmax over 3
            int r = tid - 459;
            float a0=xiS[459+3*r], a1=xiS[460+3*r], a2=xiS[461+3*r];
            float mx = fmaxf(a0, fmaxf(a1, a2));
            float e0=expf(a0-mx), e1=expf(a1-mx), e2=expf(a2-mx);
            float si = 1.0f/(e0+e1+e2);
            modes[3*r]=e0*si; modes[3*r+1]=e1*si; modes[3*r+2]=e2*si;
        }
        __syncthreads();

        // ---- E2a: norms of OLD mem rows + key norms (disjoint writes) ----
        if (tid < NM) {
            float s = 0.0f;
            for (int w = 0; w < NW; ++w) { float v = mem[tid*MS+w]; s += v*v; }
            nmo[tid] = sqrtf(s);
        } else if (tid < NM+NR) {
            int r = tid - NM; float s = 0.0f;
            for (int w = 0; w < NW; ++w) { float v = keys[r*NW+w]; s += v*v; }
            nkey[r] = sqrtf(s);
        } else if (tid == NM+NR) {
            float s = 0.0f;
            for (int w = 0; w < NW; ++w) { float v = wkey[w]; s += v*v; }
            sc[3] = sqrtf(s);
        }
        __syncthreads();

        // ---- E2b: usage update (OLD ww, OLD rw, new free gates) ----
        if (tid < NM) {
            float u = usg[tid];
            u = u + (1.0f - u)*wwO[tid];
            float psi = 1.0f;
            #pragma unroll
            for (int r = 0; r < NR; ++r) psi *= (1.0f - fgte[r]*rwS[r*NM+tid]);
            usg[tid] = u*psi;
        }
        __syncthreads();

        // ---- F1: write-content logits (OLD mem) ----
        if (tid < NM) {
            float d = 0.0f;
            for (int w = 0; w < NW; ++w) d += wkey[w]*mem[tid*MS+w];
            wcw[tid] = d/(sc[3]*nmo[tid] + EPSF) * sc[0];
        }
        __syncthreads();

        // ---- F2: softmax over 128 ----
        if (tid < 64) {
            float v = fmaxf(wcw[tid], wcw[tid+64]);
            #pragma unroll
            for (int o = 32; o > 0; o >>= 1) v = fmaxf(v, __shfl_down(v, o));
            if (tid == 0) red[0] = v;
        }
        __syncthreads();
        if (tid < NM) wcw[tid] = expf(wcw[tid] - red[0]);
        __syncthreads();
        if (tid < 64) {
            float v = wcw[tid] + wcw[tid+64];
            #pragma unroll
            for (int o = 32; o > 0; o >>= 1) v += __shfl_down(v, o);
            if (tid == 0) red[0] = 1.0f/v;
        }
        __syncthreads();
        if (tid < NM) wcw[tid] *= red[0];
        __syncthreads();

        // ---- G1: u = 5e-6 + (1-5e-6)*usage ----
        if (tid < NM) uu[tid] = 5e-6f + (1.0f - 5e-6f)*usg[tid];
        __syncthreads();

        // ---- G2: stable ascending rank (== jnp.argsort, stable) ----
        if (tid < NM) {
            float um = uu[tid]; int rk = 0;
            for (int j = 0; j < NM; ++j) {
                float uj = uu[j];
                rk += (uj < um) || (uj == um && j < tid);
            }
            rnk[tid] = rk;
            su[rk] = um;                       // ranks are a permutation
        }
        __syncthreads();

        // ---- G3: sequential inclusive cumprod (matches jnp.cumprod order) ----
        if (tid == 0) {
            float p = 1.0f;
            for (int k = 0; k < NM; ++k) { p *= su[k]; cum[k] = p; }
        }
        __syncthreads();

        // ---- G4: alloc + new write weighting ----
        if (tid < NM) {
            int rk = rnk[tid];
            float excl = (rk == 0) ? 1.0f : cum[rk-1];
            float al = (1.0f - uu[tid])*excl;
            wwN[tid] = sc[2]*(sc[1]*al + (1.0f - sc[1])*wcw[tid]);
        }
        __syncthreads();

        // ---- G5: sum(wwN) ----
        if (tid < 64) {
            float v = wwN[tid] + wwN[tid+64];
            #pragma unroll
            for (int o = 32; o > 0; o >>= 1) v += __shfl_down(v, o);
            if (tid == 0) sc[4] = v;
        }
        __syncthreads();

        // ---- H1: erase+write mem; link update (OLD prec) ----
        for (int e = tid; e < NM*NW; e += TPB) {
            int m = e >> 6, w = e & 63;
            float wm = wwN[m];
            mem[m*MS+w] = mem[m*MS+w]*(1.0f - wm*ers[w]) + wm*wvec[w];
        }
        for (int e = tid; e < NM*NM; e += TPB) {
            int i = e >> 7, j = e & 127;
            float nl = (i == j) ? 0.0f
                     : (1.0f - wwN[i] - wwN[j])*link[e] + wwN[i]*prc[j];
            link[e] = nl;
        }
        __syncthreads();

        // ---- H2: norms of NEW mem ----
        if (tid < NM) {
            float s = 0.0f;
            for (int w = 0; w < NW; ++w) { float v = mem[tid*MS+w]; s += v*v; }
            nmn[tid] = sqrtf(s);
        }
        __syncthreads();

        // ---- H3: precedence ----
        if (tid < NM) prc[tid] = (1.0f - sc[4])*prc[tid] + wwN[tid];
        __syncthreads();

        // ---- I: read-content logits (NEW mem) + per-r softmax ----
        if (tid < NR*NM) {
            int r = tid >> 7, m = tid & 127;
            float d = 0.0f;
            for (int w = 0; w < NW; ++w) d += keys[r*NW+w]*mem[m*MS+w];
            ccw[tid] = d/(nkey[r]*nmn[m] + EPSF) * rstr[r];
        }
        __syncthreads();
        if (tid < 256) {
            int r = tid >> 6, l = tid & 63;
            float v = fmaxf(ccw[r*NM+l], ccw[r*NM+l+64]);
            #pragma unroll
            for (int o = 32; o > 0; o >>= 1) v = fmaxf(v, __shfl_down(v, o));
            if (l == 0) red[r] = v;
        }
        __syncthreads();
        if (tid < NR*NM) ccw[tid] = expf(ccw[tid] - red[tid>>7]);
        __syncthreads();
        if (tid < 256) {
            int r = tid >> 6, l = tid & 63;
            float v = ccw[r*NM+l] + ccw[r*NM+l+64];
            #pragma unroll
            for (int o = 32; o > 0; o >>= 1) v += __shfl_down(v, o);
            if (l == 0) red[4+r] = 1.0f/v;
        }
        __syncthreads();
        if (tid < NR*NM) ccw[tid] *= red[4+(tid>>7)];
        __syncthreads();

        // ---- J: fwd/bwd via NEW link, OLD rw; mode mix ----
        float rwnew = 0.0f;
        if (tid < NR*NM) {
            int r = tid >> 7, m = tid & 127;
            float f = 0.0f, bw = 0.0f;
            for (int j = 0; j < NM; ++j) f  += link[m*NM+j]*rwS[r*NM+j];
            for (int i = 0; i < NM; ++i) bw += link[i*NM+m]*rwS[r*NM+i];
            rwnew = modes[3*r]*bw + modes[3*r+1]*f + modes[3*r+2]*ccw[tid];
        }
        __syncthreads();
        if (tid < NR*NM) rwS[tid] = rwnew;
        __syncthreads();

        // ---- K: read vectors (NEW rw, NEW mem) ----
        if (tid < NR*NW) {
            int r = tid >> 6, w = tid & 63;
            float s = 0.0f;
            for (int m = 0; m < NM; ++m) s += rwS[r*NM+m]*mem[m*MS+w];
            rv[tid] = s;
        }
        __syncthreads();

        // ---- L: out[j] = b_o + W_o[j,:].[h | rv]  (f32 output!) ----
        if (tid < NH) {
            const float4* wo = (const float4*)(W_o + (size_t)tid*NI);
            float acc = b_o[tid];
            #pragma unroll 4
            for (int k = 0; k < NH/4; ++k) {
                float4 w = wo[k];
                acc += w.x*hS[4*k] + w.y*hS[4*k+1] + w.z*hS[4*k+2] + w.w*hS[4*k+3];
            }
            #pragma unroll 4
            for (int k = 0; k < NR*NW/4; ++k) {
                float4 w = wo[NH/4 + k];
                acc += w.x*rv[4*k] + w.y*rv[4*k+1] + w.z*rv[4*k+2] + w.w*rv[4*k+3];
            }
            out[((size_t)b*NT + t)*NH + tid] = acc;
        }
        __syncthreads();

        // ---- M: carry copies for next step ----
        if (tid < NR*NW) inp[NH + tid] = rv[tid];
        if (tid >= 512 && tid < 512 + NM) wwO[tid-512] = wwN[tid-512];
        __syncthreads();
    }
}

extern "C" void kernel_launch(void* const* d_in, const int* in_sizes, int n_in,
                              void* d_out, int out_size, void* d_ws, size_t ws_size,
                              hipStream_t stream) {
    (void)in_sizes; (void)n_in; (void)out_size; (void)ws_size;
    const float* x    = (const float*)d_in[0];
    const float* W_ih = (const float*)d_in[1];
    const float* W_hh = (const float*)d_in[2];
    const float* b_ih = (const float*)d_in[3];
    const float* b_hh = (const float*)d_in[4];
    const float* W_xi = (const float*)d_in[5];
    const float* b_xi = (const float*)d_in[6];
    const float* W_o  = (const float*)d_in[7];
    const float* b_o  = (const float*)d_in[8];

    dnc_kernel<<<NB, TPB, 0, stream>>>(x, W_ih, W_hh, b_ih, b_hh, W_xi, b_xi,
                                       W_o, b_o, (float*)d_out,
                                       (float*)d_ws);
}

// Round 5
// 9135.862 us; speedup vs baseline: 2.7351x; 2.7351x over previous
//
#include <hip/hip_runtime.h>
#include <hip/hip_cooperative_groups.h>
#include <math.h>

namespace cg = cooperative_groups;

#define TPB 1024
#define NBLK 256
#define NBATCH 32
#define NT 64
#define NH 512
#define NM 128
#define NR 4
#define NW 64
#define NI 768          // controller input size (H + R*W)
#define NXI 471         // interface vector size
#define NG 2048         // gate rows
#define EPSF 1e-6f
#define MS 65           // mem row stride (+1 pad)

// ws layout (float offsets)
#define WS_LINK  0                               // 32 batches x 2 bufs x 128x128
#define WS_GATES (WS_LINK + NBATCH*2*NM*NM)      // 32 x 2048
#define WS_XI    (WS_GATES + (size_t)NBATCH*NG)  // 32 x 512

__device__ __forceinline__ float sigm(float x){ return 1.0f/(1.0f+expf(-x)); }
__device__ __forceinline__ float sftp(float x){ return fmaxf(x,0.0f)+log1pf(expf(-fabsf(x))); }
__device__ __forceinline__ float dot4(float4 a, float4 b){
    return a.x*b.x + a.y*b.y + a.z*b.z + a.w*b.w;
}
__device__ __forceinline__ float wave_red(float v){
    #pragma unroll
    for (int o = 32; o > 0; o >>= 1) v += __shfl_down(v, o);
    return v;
}

__global__ __launch_bounds__(TPB) void dnc_coop(
    const float* __restrict__ x, const float* __restrict__ W_ih,
    const float* __restrict__ W_hh, const float* __restrict__ b_ih,
    const float* __restrict__ b_hh, const float* __restrict__ W_xi,
    const float* __restrict__ b_xi, const float* __restrict__ W_o,
    const float* __restrict__ b_o, float* __restrict__ out,
    float* __restrict__ ws)
{
    cg::grid_group grid = cg::this_grid();

    // -------- per-block private replicated state (55 KB LDS) --------
    __shared__ float mem[NM*MS];
    __shared__ __align__(16) float hS[NH];
    __shared__ float cS[NH];
    __shared__ float rwS[NR*NM];
    __shared__ float wwO[NM], wwN[NM];
    __shared__ float usg[NM], prc[NM];
    __shared__ __align__(16) float inp[NI];      // [x_t | last_read]
    __shared__ float xiS[NXI+1];
    __shared__ float keys[NR*NW];
    __shared__ float wkey[NW], ers[NW], wvec[NW];
    __shared__ float rstr[NR], fgte[NR], modes[NR*3], nkey[NR];
    __shared__ float sc[8];               // 0:wstr 1:ag 2:wg 3:|wkey| 4:sum(ww)
    __shared__ float nmo[NM], nmn[NM];
    __shared__ float wcw[NM], uu[NM], su[NM], cum[NM];
    __shared__ int   rnk[NM];
    __shared__ float ccw[NR*NM];
    __shared__ __align__(16) float rv[NR*NW];
    __shared__ float red[8];

    const int tid = threadIdx.x;
    const int wv  = tid >> 6;             // wave id 0..15
    const int l   = tid & 63;             // lane
    const int b   = blockIdx.x >> 3;      // batch
    const int s   = blockIdx.x & 7;       // slice (same slice -> same XCD if RR)

    float* __restrict__ lkBase = ws + WS_LINK + (size_t)b*2*NM*NM;
    float* __restrict__ gatesB = ws + WS_GATES + (size_t)b*NG;
    float* __restrict__ xiB    = ws + WS_XI + (size_t)b*512;

    // -------- init (redundant identical writes across a batch's 8 blocks) ----
    for (int e = tid; e < 2*NM*NM; e += TPB) lkBase[e] = 0.0f;
    for (int e = tid; e < NM*NW; e += TPB) mem[(e>>6)*MS + (e&63)] = EPSF;
    for (int e = tid; e < NH; e += TPB){ hS[e]=0.0f; cS[e]=0.0f; }
    for (int e = tid; e < NR*NM; e += TPB) rwS[e]=0.0f;
    for (int e = tid; e < NM; e += TPB){ wwO[e]=0.0f; usg[e]=0.0f; prc[e]=0.0f; }
    for (int e = tid; e < NR*NW; e += TPB) inp[NH+e]=0.0f;
    __syncthreads();

    for (int t = 0; t < NT; ++t) {
        float* __restrict__ lkO = lkBase + (t & 1)*NM*NM;       // read (old)
        float* __restrict__ lkN = lkBase + ((t+1) & 1)*NM*NM;   // write (new)

        // ================= P1: x_t load + gates GEMV slice =================
        if (tid < NH) inp[tid] = x[((size_t)b*NT + t)*NH + tid];
        __syncthreads();
        {
            const float4* inp4 = (const float4*)inp;
            const float4* h4   = (const float4*)hS;
            float4 i0 = inp4[l], i1 = inp4[l+64], i2 = inp4[l+128];
            float4 hv0 = h4[l], hv1 = h4[l+64];
            const int rbase = s*256 + wv*16;
            for (int i = 0; i < 16; i += 2) {
                const int r0 = rbase + i, r1 = r0 + 1;
                const float4* A0 = (const float4*)(W_ih + (size_t)r0*NI);
                const float4* B0 = (const float4*)(W_hh + (size_t)r0*NH);
                const float4* A1 = (const float4*)(W_ih + (size_t)r1*NI);
                const float4* B1 = (const float4*)(W_hh + (size_t)r1*NH);
                float4 a00=A0[l], a01=A0[l+64], a02=A0[l+128];
                float4 b00=B0[l], b01=B0[l+64];
                float4 a10=A1[l], a11=A1[l+64], a12=A1[l+128];
                float4 b10=B1[l], b11=B1[l+64];
                float v0 = dot4(a00,i0)+dot4(a01,i1)+dot4(a02,i2)
                         + dot4(b00,hv0)+dot4(b01,hv1);
                float v1 = dot4(a10,i0)+dot4(a11,i1)+dot4(a12,i2)
                         + dot4(b10,hv0)+dot4(b11,hv1);
                v0 = wave_red(v0); v1 = wave_red(v1);
                if (l == 0) {
                    gatesB[r0] = v0 + b_ih[r0] + b_hh[r0];
                    gatesB[r1] = v1 + b_ih[r1] + b_hh[r1];
                }
            }
        }
        grid.sync();   // S1: gates visible to all blocks of this batch

        // ================= P2: LSTM pointwise + xi GEMV slice ==============
        if (tid < NH) {
            float ig = sigm(gatesB[tid]);
            float fg = sigm(gatesB[NH + tid]);
            float gg = tanhf(gatesB[2*NH + tid]);
            float og = sigm(gatesB[3*NH + tid]);
            float c = fg*cS[tid] + ig*gg;
            cS[tid] = c;
            hS[tid] = og*tanhf(c);
        }
        __syncthreads();
        {
            const float4* h4 = (const float4*)hS;
            float4 hv0 = h4[l], hv1 = h4[l+64];
            const int rend = (s*59 + 59 < NXI) ? (s*59 + 59) : NXI;
            for (int row = s*59 + wv; row < rend; row += 16) {
                const float4* Wc = (const float4*)(W_xi + (size_t)row*NH);
                float v = dot4(Wc[l], hv0) + dot4(Wc[l+64], hv1);
                v = wave_red(v);
                if (l == 0) xiB[row] = v + b_xi[row];
            }
        }
        grid.sync();   // S2: xi visible to all blocks of this batch

        // ================= P3: replicated DNC machinery ====================
        for (int e = tid; e < NXI; e += TPB) xiS[e] = xiB[e];
        __syncthreads();

        // E1: unpack interface
        if (tid < 256)       keys[tid] = tanhf(xiS[tid]);
        else if (tid < 260)  rstr[tid-256] = sftp(xiS[tid]);
        else if (tid < 324)  wkey[tid-260] = tanhf(xiS[tid]);
        else if (tid == 324) sc[0] = sftp(xiS[324]);
        else if (tid < 389)  ers[tid-325] = sigm(xiS[tid]);
        else if (tid < 453)  wvec[tid-389] = tanhf(xiS[tid]);
        else if (tid < 457)  fgte[tid-453] = sigm(xiS[tid]);
        else if (tid == 457) sc[1] = sigm(xiS[457]);
        else if (tid == 458) sc[2] = sigm(xiS[458]);
        else if (tid < 463) {
            int r = tid - 459;
            float a0=xiS[459+3*r], a1=xiS[460+3*r], a2=xiS[461+3*r];
            float mx = fmaxf(a0, fmaxf(a1, a2));
            float e0=expf(a0-mx), e1=expf(a1-mx), e2=expf(a2-mx);
            float si = 1.0f/(e0+e1+e2);
            modes[3*r]=e0*si; modes[3*r+1]=e1*si; modes[3*r+2]=e2*si;
        }
        __syncthreads();

        // E2a: old mem norms + key norms
        if (tid < NM) {
            float ssum = 0.0f;
            for (int w = 0; w < NW; ++w) { float v = mem[tid*MS+w]; ssum += v*v; }
            nmo[tid] = sqrtf(ssum);
        } else if (tid < NM+NR) {
            int r = tid - NM; float ssum = 0.0f;
            for (int w = 0; w < NW; ++w) { float v = keys[r*NW+w]; ssum += v*v; }
            nkey[r] = sqrtf(ssum);
        } else if (tid == NM+NR) {
            float ssum = 0.0f;
            for (int w = 0; w < NW; ++w) { float v = wkey[w]; ssum += v*v; }
            sc[3] = sqrtf(ssum);
        }
        __syncthreads();

        // E2b: usage update
        if (tid < NM) {
            float u = usg[tid];
            u = u + (1.0f - u)*wwO[tid];
            float psi = 1.0f;
            #pragma unroll
            for (int r = 0; r < NR; ++r) psi *= (1.0f - fgte[r]*rwS[r*NM+tid]);
            usg[tid] = u*psi;
        }
        __syncthreads();

        // F1: write-content logits
        if (tid < NM) {
            float d = 0.0f;
            for (int w = 0; w < NW; ++w) d += wkey[w]*mem[tid*MS+w];
            wcw[tid] = d/(sc[3]*nmo[tid] + EPSF) * sc[0];
        }
        __syncthreads();
        // F2: softmax over 128
        if (tid < 64) {
            float v = fmaxf(wcw[tid], wcw[tid+64]);
            #pragma unroll
            for (int o = 32; o > 0; o >>= 1) v = fmaxf(v, __shfl_down(v, o));
            if (tid == 0) red[0] = v;
        }
        __syncthreads();
        if (tid < NM) wcw[tid] = expf(wcw[tid] - red[0]);
        __syncthreads();
        if (tid < 64) {
            float v = wave_red(wcw[tid] + wcw[tid+64]);
            if (tid == 0) red[0] = 1.0f/v;
        }
        __syncthreads();
        if (tid < NM) wcw[tid] *= red[0];
        __syncthreads();

        // G1: u
        if (tid < NM) uu[tid] = 5e-6f + (1.0f - 5e-6f)*usg[tid];
        __syncthreads();
        // G2: stable rank
        if (tid < NM) {
            float um = uu[tid]; int rk = 0;
            for (int j = 0; j < NM; ++j) {
                float uj = uu[j];
                rk += (uj < um) || (uj == um && j < tid);
            }
            rnk[tid] = rk;
            su[rk] = um;
        }
        __syncthreads();
        // G3: sequential cumprod
        if (tid == 0) {
            float p = 1.0f;
            for (int k = 0; k < NM; ++k) { p *= su[k]; cum[k] = p; }
        }
        __syncthreads();
        // G4: alloc + write weighting
        if (tid < NM) {
            int rk = rnk[tid];
            float excl = (rk == 0) ? 1.0f : cum[rk-1];
            float al = (1.0f - uu[tid])*excl;
            wwN[tid] = sc[2]*(sc[1]*al + (1.0f - sc[1])*wcw[tid]);
        }
        __syncthreads();
        // G5: sum(wwN)
        if (tid < 64) {
            float v = wave_red(wwN[tid] + wwN[tid+64]);
            if (tid == 0) sc[4] = v;
        }
        __syncthreads();

        // H1: erase+write mem; link update lkO -> lkN (no RMW race: dbuf)
        for (int e = tid; e < NM*NW; e += TPB) {
            int m = e >> 6, w = e & 63;
            float wm = wwN[m];
            mem[m*MS+w] = mem[m*MS+w]*(1.0f - wm*ers[w]) + wm*wvec[w];
        }
        for (int e = tid; e < NM*NM; e += TPB) {
            int i = e >> 7, j = e & 127;
            float nl = (i == j) ? 0.0f
                     : (1.0f - wwN[i] - wwN[j])*lkO[e] + wwN[i]*prc[j];
            lkN[e] = nl;
        }
        __syncthreads();
        // H2: new mem norms
        if (tid < NM) {
            float ssum = 0.0f;
            for (int w = 0; w < NW; ++w) { float v = mem[tid*MS+w]; ssum += v*v; }
            nmn[tid] = sqrtf(ssum);
        }
        __syncthreads();
        // H3: precedence
        if (tid < NM) prc[tid] = (1.0f - sc[4])*prc[tid] + wwN[tid];
        __syncthreads();

        // I: read-content logits + per-r softmax
        if (tid < NR*NM) {
            int r = tid >> 7, m = tid & 127;
            float d = 0.0f;
            for (int w = 0; w < NW; ++w) d += keys[r*NW+w]*mem[m*MS+w];
            ccw[tid] = d/(nkey[r]*nmn[m] + EPSF) * rstr[r];
        }
        __syncthreads();
        if (tid < 256) {
            int r = tid >> 6, ll = tid & 63;
            float v = fmaxf(ccw[r*NM+ll], ccw[r*NM+ll+64]);
            #pragma unroll
            for (int o = 32; o > 0; o >>= 1) v = fmaxf(v, __shfl_down(v, o));
            if (ll == 0) red[r] = v;
        }
        __syncthreads();
        if (tid < NR*NM) ccw[tid] = expf(ccw[tid] - red[tid>>7]);
        __syncthreads();
        if (tid < 256) {
            int r = tid >> 6, ll = tid & 63;
            float v = wave_red(ccw[r*NM+ll] + ccw[r*NM+ll+64]);
            if (ll == 0) red[4+r] = 1.0f/v;
        }
        __syncthreads();
        if (tid < NR*NM) ccw[tid] *= red[4+(tid>>7)];
        __syncthreads();

        // J: fwd/bwd via NEW link (lkN), OLD rw
        float rwnew = 0.0f;
        if (tid < NR*NM) {
            int r = tid >> 7, m = tid & 127;
            float f = 0.0f, bw = 0.0f;
            for (int j = 0; j < NM; ++j) f  += lkN[m*NM+j]*rwS[r*NM+j];
            for (int i = 0; i < NM; ++i) bw += lkN[i*NM+m]*rwS[r*NM+i];
            rwnew = modes[3*r]*bw + modes[3*r+1]*f + modes[3*r+2]*ccw[tid];
        }
        __syncthreads();
        if (tid < NR*NM) rwS[tid] = rwnew;
        __syncthreads();

        // K: read vectors
        if (tid < NR*NW) {
            int r = tid >> 6, w = tid & 63;
            float ssum = 0.0f;
            for (int m = 0; m < NM; ++m) ssum += rwS[r*NM+m]*mem[m*MS+w];
            rv[tid] = ssum;
        }
        __syncthreads();

        // ================= out GEMV slice (64 rows/block) ==================
        {
            const float4* h4  = (const float4*)hS;
            const float4* rv4 = (const float4*)rv;
            float4 hv0 = h4[l], hv1 = h4[l+64], rvv = rv4[l];
            const int rbase = s*64 + wv*4;
            for (int i = 0; i < 4; ++i) {
                const int row = rbase + i;
                const float4* Wo = (const float4*)(W_o + (size_t)row*NI);
                float v = dot4(Wo[l],hv0) + dot4(Wo[l+64],hv1) + dot4(Wo[l+128],rvv);
                v = wave_red(v);
                if (l == 0) out[((size_t)b*NT + t)*NH + row] = v + b_o[row];
            }
        }
        __syncthreads();

        // M: carries (next P1's post-x-load __syncthreads orders these reads)
        if (tid < NR*NW) inp[NH + tid] = rv[tid];
        else if (tid < NR*NW + NM) wwO[tid - NR*NW] = wwN[tid - NR*NW];
        __syncthreads();
    }
}

extern "C" void kernel_launch(void* const* d_in, const int* in_sizes, int n_in,
                              void* d_out, int out_size, void* d_ws, size_t ws_size,
                              hipStream_t stream) {
    (void)in_sizes; (void)n_in; (void)out_size; (void)ws_size;
    const float* x    = (const float*)d_in[0];
    const float* W_ih = (const float*)d_in[1];
    const float* W_hh = (const float*)d_in[2];
    const float* b_ih = (const float*)d_in[3];
    const float* b_hh = (const float*)d_in[4];
    const float* W_xi = (const float*)d_in[5];
    const float* b_xi = (const float*)d_in[6];
    const float* W_o  = (const float*)d_in[7];
    const float* b_o  = (const float*)d_in[8];
    float* out = (float*)d_out;
    float* ws  = (float*)d_ws;

    void* args[] = { (void*)&x, (void*)&W_ih, (void*)&W_hh, (void*)&b_ih,
                     (void*)&b_hh, (void*)&W_xi, (void*)&b_xi, (void*)&W_o,
                     (void*)&b_o, (void*)&out, (void*)&ws };
    hipLaunchCooperativeKernel((void*)dnc_coop, dim3(NBLK), dim3(TPB),
                               args, 0, stream);
}

// Round 6
// 8944.012 us; speedup vs baseline: 2.7937x; 1.0215x over previous
//
#include <hip/hip_runtime.h>
#include <hip/hip_cooperative_groups.h>
#include <math.h>

namespace cg = cooperative_groups;

#define TPB 1024
#define NBLK 256
#define NBATCH 32
#define NT 64
#define NH 512
#define NM 128
#define NR 4
#define NW 64
#define NI 768          // controller input size (H + R*W)
#define NXI 471         // interface vector size
#define NG 2048         // gate rows
#define EPSF 1e-6f
#define MS 65           // mem row stride (+1 pad)

// ws layout (float offsets)
#define WS_LINK  0                                   // 32 x 2 x 128x128
#define WS_GATES (WS_LINK + NBATCH*2*NM*NM)          // 32 x 2 x 2048 (parity dbuf)
#define WS_CNT   (WS_GATES + (size_t)NBATCH*2*NG)    // 32 uint counters

__device__ __forceinline__ float sigm(float x){ return 1.0f/(1.0f+expf(-x)); }
__device__ __forceinline__ float sftp(float x){ return fmaxf(x,0.0f)+log1pf(expf(-fabsf(x))); }
__device__ __forceinline__ float dot4(float4 a, float4 b){
    return a.x*b.x + a.y*b.y + a.z*b.z + a.w*b.w;
}
__device__ __forceinline__ float wave_red(float v){
    #pragma unroll
    for (int o = 32; o > 0; o >>= 1) v += __shfl_down(v, o);
    return v;
}

__global__ __launch_bounds__(TPB) void dnc_flag(
    const float* __restrict__ x, const float* __restrict__ W_ih,
    const float* __restrict__ W_hh, const float* __restrict__ b_ih,
    const float* __restrict__ b_hh, const float* __restrict__ W_xi,
    const float* __restrict__ b_xi, const float* __restrict__ W_o,
    const float* __restrict__ b_o, float* __restrict__ out,
    float* __restrict__ ws)
{
    cg::grid_group grid = cg::this_grid();

    // -------- per-block private replicated state --------
    __shared__ float mem[NM*MS];
    __shared__ __align__(16) float hS[NH];
    __shared__ float cS[NH];
    __shared__ float rwS[NR*NM];
    __shared__ float wwO[NM], wwN[NM];
    __shared__ float usg[NM], prc[NM];
    __shared__ __align__(16) float inp[NI];      // [x_t | last_read]
    __shared__ float xiS[NXI+1];
    __shared__ float keys[NR*NW];
    __shared__ float wkey[NW], ers[NW], wvec[NW];
    __shared__ float rstr[NR], fgte[NR], modes[NR*3], nkey[NR];
    __shared__ float sc[8];               // 0:wstr 1:ag 2:wg 3:|wkey| 4:sum(ww)
    __shared__ float nmo[NM], nmn[NM];
    __shared__ float wcw[NM], uu[NM], su[NM], cum[NM];
    __shared__ int   rnk[NM];
    __shared__ float ccw[NR*NM];
    __shared__ float fwdT[NR*NM];
    __shared__ __align__(16) float rv[NR*NW];
    __shared__ float red[8];

    const int tid = threadIdx.x;
    const int wv  = tid >> 6;             // wave id 0..15
    const int l   = tid & 63;             // lane
    const int b   = blockIdx.x >> 3;      // batch
    const int s   = blockIdx.x & 7;       // slice (RR -> XCD affinity)

    float* __restrict__ lkBase = ws + WS_LINK + (size_t)b*2*NM*NM;
    unsigned int* __restrict__ cnt = (unsigned int*)(ws + WS_CNT);

    // -------- init --------
    for (int e = tid; e < 2*NM*NM; e += TPB) lkBase[e] = 0.0f;
    for (int e = tid; e < NM*NW; e += TPB) mem[(e>>6)*MS + (e&63)] = EPSF;
    for (int e = tid; e < NH; e += TPB){ hS[e]=0.0f; cS[e]=0.0f; }
    for (int e = tid; e < NR*NM; e += TPB) rwS[e]=0.0f;
    for (int e = tid; e < NM; e += TPB){ wwO[e]=0.0f; usg[e]=0.0f; prc[e]=0.0f; }
    for (int e = tid; e < NR*NW; e += TPB) inp[NH+e]=0.0f;
    if (s == 0 && tid == 0) cnt[b] = 0u;
    __syncthreads();
    grid.sync();   // one-time: counters zeroed + link zeroed visible

    for (int t = 0; t < NT; ++t) {
        float* __restrict__ lkO = lkBase + (t & 1)*NM*NM;       // read (old)
        float* __restrict__ lkN = lkBase + ((t+1) & 1)*NM*NM;   // write (new)
        float* __restrict__ gatesBuf = ws + WS_GATES + ((size_t)b*2 + (t & 1))*NG;

        // ================= P1: x_t load + gates GEMV slice =================
        if (tid < NH) inp[tid] = x[((size_t)b*NT + t)*NH + tid];
        __syncthreads();
        {
            const float4* inp4 = (const float4*)inp;
            const float4* h4   = (const float4*)hS;
            float4 i0 = inp4[l], i1 = inp4[l+64], i2 = inp4[l+128];
            float4 hv0 = h4[l], hv1 = h4[l+64];
            const int rbase = s*256 + wv*16;
            for (int i = 0; i < 16; i += 2) {
                const int r0 = rbase + i, r1 = r0 + 1;
                const float4* A0 = (const float4*)(W_ih + (size_t)r0*NI);
                const float4* B0 = (const float4*)(W_hh + (size_t)r0*NH);
                const float4* A1 = (const float4*)(W_ih + (size_t)r1*NI);
                const float4* B1 = (const float4*)(W_hh + (size_t)r1*NH);
                float4 a00=A0[l], a01=A0[l+64], a02=A0[l+128];
                float4 b00=B0[l], b01=B0[l+64];
                float4 a10=A1[l], a11=A1[l+64], a12=A1[l+128];
                float4 b10=B1[l], b11=B1[l+64];
                float v0 = dot4(a00,i0)+dot4(a01,i1)+dot4(a02,i2)
                         + dot4(b00,hv0)+dot4(b01,hv1);
                float v1 = dot4(a10,i0)+dot4(a11,i1)+dot4(a12,i2)
                         + dot4(b10,hv0)+dot4(b11,hv1);
                v0 = wave_red(v0); v1 = wave_red(v1);
                if (l == 0) {
                    gatesBuf[r0] = v0 + b_ih[r0] + b_hh[r0];
                    gatesBuf[r1] = v1 + b_ih[r1] + b_hh[r1];
                }
            }
        }
        __syncthreads();   // all slice stores drained (vmcnt(0) before barrier)

        // ===== S1: 8-block flag sync (counter chain orders t+2 overwrites) ====
        if (tid == 0) {
            __hip_atomic_fetch_add(&cnt[b], 1u, __ATOMIC_RELEASE,
                                   __HIP_MEMORY_SCOPE_AGENT);
            const unsigned int target = 8u*(unsigned)(t+1);
            while (__hip_atomic_load(&cnt[b], __ATOMIC_RELAXED,
                                     __HIP_MEMORY_SCOPE_AGENT) < target)
                __builtin_amdgcn_s_sleep(2);
            (void)__hip_atomic_load(&cnt[b], __ATOMIC_ACQUIRE,
                                    __HIP_MEMORY_SCOPE_AGENT);
        }
        __syncthreads();

        // ================= P2: LSTM pointwise (full, replicated) ===========
        if (tid < NH) {
            float ig = sigm(gatesBuf[tid]);
            float fg = sigm(gatesBuf[NH + tid]);
            float gg = tanhf(gatesBuf[2*NH + tid]);
            float og = sigm(gatesBuf[3*NH + tid]);
            float c = fg*cS[tid] + ig*gg;
            cS[tid] = c;
            hS[tid] = og*tanhf(c);
        }
        __syncthreads();

        // ================= P2b: xi GEMV (full, replicated) =================
        {
            const float4* h4 = (const float4*)hS;
            float4 hv0 = h4[l], hv1 = h4[l+64];
            for (int row = wv; row < NXI; row += 16) {
                const float4* Wc = (const float4*)(W_xi + (size_t)row*NH);
                float v = dot4(Wc[l], hv0) + dot4(Wc[l+64], hv1);
                v = wave_red(v);
                if (l == 0) xiS[row] = v + b_xi[row];
            }
        }
        __syncthreads();

        // ================= P3: replicated DNC machinery ====================
        // E1: unpack interface
        if (tid < 256)       keys[tid] = tanhf(xiS[tid]);
        else if (tid < 260)  rstr[tid-256] = sftp(xiS[tid]);
        else if (tid < 324)  wkey[tid-260] = tanhf(xiS[tid]);
        else if (tid == 324) sc[0] = sftp(xiS[324]);
        else if (tid < 389)  ers[tid-325] = sigm(xiS[tid]);
        else if (tid < 453)  wvec[tid-389] = tanhf(xiS[tid]);
        else if (tid < 457)  fgte[tid-453] = sigm(xiS[tid]);
        else if (tid == 457) sc[1] = sigm(xiS[457]);
        else if (tid == 458) sc[2] = sigm(xiS[458]);
        else if (tid < 463) {
            int r = tid - 459;
            float a0=xiS[459+3*r], a1=xiS[460+3*r], a2=xiS[461+3*r];
            float mx = fmaxf(a0, fmaxf(a1, a2));
            float e0=expf(a0-mx), e1=expf(a1-mx), e2=expf(a2-mx);
            float si = 1.0f/(e0+e1+e2);
            modes[3*r]=e0*si; modes[3*r+1]=e1*si; modes[3*r+2]=e2*si;
        }
        __syncthreads();

        // E2a: old mem norms + key norms
        if (tid < NM) {
            float ssum = 0.0f;
            for (int w = 0; w < NW; ++w) { float v = mem[tid*MS+w]; ssum += v*v; }
            nmo[tid] = sqrtf(ssum);
        } else if (tid < NM+NR) {
            int r = tid - NM; float ssum = 0.0f;
            for (int w = 0; w < NW; ++w) { float v = keys[r*NW+w]; ssum += v*v; }
            nkey[r] = sqrtf(ssum);
        } else if (tid == NM+NR) {
            float ssum = 0.0f;
            for (int w = 0; w < NW; ++w) { float v = wkey[w]; ssum += v*v; }
            sc[3] = sqrtf(ssum);
        }
        __syncthreads();

        // E2b: usage update
        if (tid < NM) {
            float u = usg[tid];
            u = u + (1.0f - u)*wwO[tid];
            float psi = 1.0f;
            #pragma unroll
            for (int r = 0; r < NR; ++r) psi *= (1.0f - fgte[r]*rwS[r*NM+tid]);
            usg[tid] = u*psi;
        }
        __syncthreads();

        // F1: write-content logits
        if (tid < NM) {
            float d = 0.0f;
            for (int w = 0; w < NW; ++w) d += wkey[w]*mem[tid*MS+w];
            wcw[tid] = d/(sc[3]*nmo[tid] + EPSF) * sc[0];
        }
        __syncthreads();
        // F2: softmax over 128
        if (tid < 64) {
            float v = fmaxf(wcw[tid], wcw[tid+64]);
            #pragma unroll
            for (int o = 32; o > 0; o >>= 1) v = fmaxf(v, __shfl_down(v, o));
            if (tid == 0) red[0] = v;
        }
        __syncthreads();
        if (tid < NM) wcw[tid] = expf(wcw[tid] - red[0]);
        __syncthreads();
        if (tid < 64) {
            float v = wave_red(wcw[tid] + wcw[tid+64]);
            if (tid == 0) red[0] = 1.0f/v;
        }
        __syncthreads();
        if (tid < NM) wcw[tid] *= red[0];
        __syncthreads();

        // G1: u
        if (tid < NM) uu[tid] = 5e-6f + (1.0f - 5e-6f)*usg[tid];
        __syncthreads();
        // G2: stable rank
        if (tid < NM) {
            float um = uu[tid]; int rk = 0;
            for (int j = 0; j < NM; ++j) {
                float uj = uu[j];
                rk += (uj < um) || (uj == um && j < tid);
            }
            rnk[tid] = rk;
            su[rk] = um;
        }
        __syncthreads();
        // G3: product scan via wave-0 shfl (assoc. reorder ok within tol)
        if (tid < 64) {
            float a = su[tid], bb = su[64+tid];
            #pragma unroll
            for (int o = 1; o < 64; o <<= 1) {
                float ta = __shfl_up(a, o);
                float tb = __shfl_up(bb, o);
                if (tid >= o) { a *= ta; bb *= tb; }
            }
            float P0 = __shfl(a, 63);
            cum[tid] = a;
            cum[64+tid] = P0*bb;
        }
        __syncthreads();
        // G4: alloc + write weighting
        if (tid < NM) {
            int rk = rnk[tid];
            float excl = (rk == 0) ? 1.0f : cum[rk-1];
            float al = (1.0f - uu[tid])*excl;
            wwN[tid] = sc[2]*(sc[1]*al + (1.0f - sc[1])*wcw[tid]);
        }
        __syncthreads();
        // G5: sum(wwN)
        if (tid < 64) {
            float v = wave_red(wwN[tid] + wwN[tid+64]);
            if (tid == 0) sc[4] = v;
        }
        __syncthreads();

        // H1: erase+write mem; link update lkO -> lkN
        for (int e = tid; e < NM*NW; e += TPB) {
            int m = e >> 6, w = e & 63;
            float wm = wwN[m];
            mem[m*MS+w] = mem[m*MS+w]*(1.0f - wm*ers[w]) + wm*wvec[w];
        }
        for (int e = tid; e < NM*NM; e += TPB) {
            int i = e >> 7, j = e & 127;
            float nl = (i == j) ? 0.0f
                     : (1.0f - wwN[i] - wwN[j])*lkO[e] + wwN[i]*prc[j];
            lkN[e] = nl;
        }
        __syncthreads();
        // H2: new mem norms
        if (tid < NM) {
            float ssum = 0.0f;
            for (int w = 0; w < NW; ++w) { float v = mem[tid*MS+w]; ssum += v*v; }
            nmn[tid] = sqrtf(ssum);
        }
        __syncthreads();
        // H3: precedence
        if (tid < NM) prc[tid] = (1.0f - sc[4])*prc[tid] + wwN[tid];
        __syncthreads();

        // I: read-content logits + per-r softmax
        if (tid < NR*NM) {
            int r = tid >> 7, m = tid & 127;
            float d = 0.0f;
            for (int w = 0; w < NW; ++w) d += keys[r*NW+w]*mem[m*MS+w];
            ccw[tid] = d/(nkey[r]*nmn[m] + EPSF) * rstr[r];
        }
        __syncthreads();
        if (tid < 256) {
            int r = tid >> 6, ll = tid & 63;
            float v = fmaxf(ccw[r*NM+ll], ccw[r*NM+ll+64]);
            #pragma unroll
            for (int o = 32; o > 0; o >>= 1) v = fmaxf(v, __shfl_down(v, o));
            if (ll == 0) red[r] = v;
        }
        __syncthreads();
        if (tid < NR*NM) ccw[tid] = expf(ccw[tid] - red[tid>>7]);
        __syncthreads();
        if (tid < 256) {
            int r = tid >> 6, ll = tid & 63;
            float v = wave_red(ccw[r*NM+ll] + ccw[r*NM+ll+64]);
            if (ll == 0) red[4+r] = 1.0f/v;
        }
        __syncthreads();
        if (tid < NR*NM) ccw[tid] *= red[4+(tid>>7)];
        __syncthreads();

        // J1: fwd[p] = link[m,:].rw[r,:] — wave-parallel over j (coalesced)
        {
            const int p0 = wv*32;
            for (int i = 0; i < 32; ++i) {
                const int p = p0 + i, r = p >> 7, m = p & 127;
                float partial = lkN[m*NM + l]*rwS[r*NM + l]
                              + lkN[m*NM + 64 + l]*rwS[r*NM + 64 + l];
                partial = wave_red(partial);
                if (l == 0) fwdT[p] = partial;
            }
        }
        __syncthreads();
        // J2: bwd (coalesced over m) + mode mix
        float rwnew = 0.0f;
        if (tid < NR*NM) {
            int r = tid >> 7, m = tid & 127;
            float bw = 0.0f;
            for (int i = 0; i < NM; ++i) bw += lkN[i*NM+m]*rwS[r*NM+i];
            rwnew = modes[3*r]*bw + modes[3*r+1]*fwdT[tid] + modes[3*r+2]*ccw[tid];
        }
        __syncthreads();
        if (tid < NR*NM) rwS[tid] = rwnew;
        __syncthreads();

        // K: read vectors
        if (tid < NR*NW) {
            int r = tid >> 6, w = tid & 63;
            float ssum = 0.0f;
            for (int m = 0; m < NM; ++m) ssum += rwS[r*NM+m]*mem[m*MS+w];
            rv[tid] = ssum;
        }
        __syncthreads();

        // ================= out GEMV slice (64 rows/block) ==================
        {
            const float4* h4  = (const float4*)hS;
            const float4* rv4 = (const float4*)rv;
            float4 hv0 = h4[l], hv1 = h4[l+64], rvv = rv4[l];
            const int rbase = s*64 + wv*4;
            for (int i = 0; i < 4; ++i) {
                const int row = rbase + i;
                const float4* Wo = (const float4*)(W_o + (size_t)row*NI);
                float v = dot4(Wo[l],hv0) + dot4(Wo[l+64],hv1) + dot4(Wo[l+128],rvv);
                v = wave_red(v);
                if (l == 0) out[((size_t)b*NT + t)*NH + row] = v + b_o[row];
            }
        }
        __syncthreads();

        // M: carries
        if (tid < NR*NW) inp[NH + tid] = rv[tid];
        else if (tid < NR*NW + NM) wwO[tid - NR*NW] = wwN[tid - NR*NW];
        __syncthreads();
    }
}

extern "C" void kernel_launch(void* const* d_in, const int* in_sizes, int n_in,
                              void* d_out, int out_size, void* d_ws, size_t ws_size,
                              hipStream_t stream) {
    (void)in_sizes; (void)n_in; (void)out_size; (void)ws_size;
    const float* x    = (const float*)d_in[0];
    const float* W_ih = (const float*)d_in[1];
    const float* W_hh = (const float*)d_in[2];
    const float* b_ih = (const float*)d_in[3];
    const float* b_hh = (const float*)d_in[4];
    const float* W_xi = (const float*)d_in[5];
    const float* b_xi = (const float*)d_in[6];
    const float* W_o  = (const float*)d_in[7];
    const float* b_o  = (const float*)d_in[8];
    float* out = (float*)d_out;
    float* ws  = (float*)d_ws;

    void* args[] = { (void*)&x, (void*)&W_ih, (void*)&W_hh, (void*)&b_ih,
                     (void*)&b_hh, (void*)&W_xi, (void*)&b_xi, (void*)&W_o,
                     (void*)&b_o, (void*)&out, (void*)&ws };
    hipLaunchCooperativeKernel((void*)dnc_flag, dim3(NBLK), dim3(TPB),
                               args, 0, stream);
}